// Round 10
// baseline (793.212 us; speedup 1.0000x reference)
//
#include <hip/hip_runtime.h>
#include <hip/hip_bf16.h>
#include <hip/hip_fp16.h>

// GCN: 3 layers of  h = relu(in_norm * A_pull( (out_norm*x) @ W ) + b)
// then seg_output = (mean_n h3) @ Wp^T + bp  and  CAM = Wp @ h3^T.
// Preprocessing: bucketed CSR (256-node buckets), no scattered global atomics
// (gfx950 atomics write through L2 at ~0.7 TB/s of 32B sectors [R1/R2/R4]).
// agg is memory-bound at its FETCH floor [R6/R7]. All h tensors fp16.
// CAM = MFMA GEMM (split-fp16 Wp: hi+residual chains -> no Wp quantization
// error) with fused colsum. [R8: LDS-bound; R9: SMEM-latency-bound — MFMA
// streams at the memory floor instead.]

#define HDIM 128
#define NCLS 40
#define BSH 8
#define BSZ 256          // nodes per bucket
#define KMAX 512
#define EPB 4096         // edges per scatter/count block

typedef _Float16 half8 __attribute__((ext_vector_type(8)));
typedef float f32x4 __attribute__((ext_vector_type(4)));

// ---------------- graph preprocessing ----------------

__global__ void zero_kernel(int* __restrict__ p, int n) {
    int i = blockIdx.x * blockDim.x + threadIdx.x;
    if (i < n) p[i] = 0;
}

// per-block LDS bucket histograms (dst and src), merged with contiguous atomics
__global__ __launch_bounds__(256) void bucket_count_kernel(
        const int* __restrict__ src, const int* __restrict__ dst,
        int* __restrict__ bcnt, int* __restrict__ sbcnt, int K, int E) {
    __shared__ int lc[KMAX], ls[KMAX];
    const int tid = threadIdx.x;
    lc[tid] = 0; lc[tid + 256] = 0; ls[tid] = 0; ls[tid + 256] = 0;
    __syncthreads();
    const int base = blockIdx.x * EPB;
    const int lim = min(EPB, E - base);
    for (int i = tid; i < lim; i += 256) {
        atomicAdd(&lc[dst[base + i] >> BSH], 1);
        atomicAdd(&ls[src[base + i] >> BSH], 1);
    }
    __syncthreads();
    for (int t = tid; t < K; t += 256) {
        if (lc[t]) atomicAdd(&bcnt[t], lc[t]);
        if (ls[t]) atomicAdd(&sbcnt[t], ls[t]);
    }
}

// one wave: sequential 64-chunk exclusive scan of both arrays (K <= KMAX)
__global__ void bucket_scan_kernel(const int* __restrict__ a, const int* __restrict__ b,
                                   int* __restrict__ abase, int* __restrict__ bbase, int K) {
    const int lane = threadIdx.x;   // blockDim = 64
    int ca = 0, cb = 0;
    for (int base = 0; base < K; base += 64) {
        int va = (base + lane < K) ? a[base + lane] : 0;
        int vb = (base + lane < K) ? b[base + lane] : 0;
        int ia = va, ib = vb;
        #pragma unroll
        for (int d = 1; d < 64; d <<= 1) {
            int oa = __shfl_up(ia, d, 64);
            int ob = __shfl_up(ib, d, 64);
            if (lane >= d) { ia += oa; ib += ob; }
        }
        if (base + lane < K) { abase[base + lane] = ca + ia - va; bbase[base + lane] = cb + ib - vb; }
        ca += __shfl(ia, 63, 64);
        cb += __shfl(ib, 63, 64);
    }
    if (lane == 0) { abase[K] = ca; bbase[K] = cb; }
}

// re-count in LDS, reserve contiguous runs, write bucketed records
__global__ __launch_bounds__(256) void bucket_scatter_kernel(
        const int* __restrict__ src, const int* __restrict__ dst,
        const int* __restrict__ bbase, const int* __restrict__ sbase,
        int* __restrict__ bcur, int* __restrict__ scur,
        int2* __restrict__ dbuf, int* __restrict__ sbuf, int K, int E) {
    __shared__ int lc[KMAX], lb[KMAX], ls[KMAX], lsb[KMAX];
    const int tid = threadIdx.x;
    lc[tid] = 0; lc[tid + 256] = 0; ls[tid] = 0; ls[tid + 256] = 0;
    __syncthreads();
    const int base = blockIdx.x * EPB;
    const int lim = min(EPB, E - base);
    for (int i = tid; i < lim; i += 256) {
        atomicAdd(&lc[dst[base + i] >> BSH], 1);
        atomicAdd(&ls[src[base + i] >> BSH], 1);
    }
    __syncthreads();
    for (int t = tid; t < K; t += 256) {
        lb[t]  = bbase[t] + (lc[t] ? atomicAdd(&bcur[t], lc[t]) : 0);
        lsb[t] = sbase[t] + (ls[t] ? atomicAdd(&scur[t], ls[t]) : 0);
    }
    __syncthreads();
    lc[tid] = 0; lc[tid + 256] = 0; ls[tid] = 0; ls[tid + 256] = 0;
    __syncthreads();
    for (int i = tid; i < lim; i += 256) {
        int d = dst[base + i], s = src[base + i];
        int kd = d >> BSH, ks = s >> BSH;
        int r = atomicAdd(&lc[kd], 1);
        dbuf[lb[kd] + r] = make_int2(d, s);
        int r2 = atomicAdd(&ls[ks], 1);
        sbuf[lsb[ks] + r2] = s;
    }
}

// one block per dst-bucket: histogram -> scan -> row_ptr/in_norm -> ranks -> col
__global__ __launch_bounds__(256) void build_csr_kernel(
        const int2* __restrict__ dbuf, const int* __restrict__ bbase,
        int* __restrict__ row_ptr, float* __restrict__ in_norm,
        int* __restrict__ col, int N, int K, int E) {
    __shared__ int cnt[BSZ], lsc[BSZ];
    __shared__ int wsum[4];
    const int k = blockIdx.x, tid = threadIdx.x;
    const int node0 = k << BSH;
    const int beg = bbase[k], end = bbase[k + 1];
    cnt[tid] = 0;
    __syncthreads();
    for (int i = beg + tid; i < end; i += 256)
        atomicAdd(&cnt[dbuf[i].x & (BSZ - 1)], 1);
    __syncthreads();
    const int c0 = cnt[tid];
    int incl = c0;
    const int lane = tid & 63, w = tid >> 6;
    #pragma unroll
    for (int d = 1; d < 64; d <<= 1) {
        int o = __shfl_up(incl, d, 64);
        if (lane >= d) incl += o;
    }
    if (lane == 63) wsum[w] = incl;
    __syncthreads();
    int off = 0;
    for (int j = 0; j < w; ++j) off += wsum[j];
    const int excl = off + incl - c0;
    lsc[tid] = excl;
    const int node = node0 + tid;
    if (node < N) { row_ptr[node] = beg + excl; in_norm[node] = 1.0f / sqrtf((float)max(c0, 1)); }
    if (k == K - 1 && tid == 0) row_ptr[N] = E;
    __syncthreads();
    cnt[tid] = 0;
    __syncthreads();
    for (int i = beg + tid; i < end; i += 256) {
        int2 e = dbuf[i];
        int local = e.x & (BSZ - 1);
        int r = atomicAdd(&cnt[local], 1);
        col[beg + lsc[local] + r] = e.y;
    }
}

// one block per src-bucket: histogram -> out_norm
__global__ __launch_bounds__(256) void outdeg_kernel(
        const int* __restrict__ sbuf, const int* __restrict__ sbase,
        float* __restrict__ out_norm, int N) {
    __shared__ int cnt[BSZ];
    const int k = blockIdx.x, tid = threadIdx.x;
    const int beg = sbase[k], end = sbase[k + 1];
    cnt[tid] = 0;
    __syncthreads();
    for (int i = beg + tid; i < end; i += 256)
        atomicAdd(&cnt[sbuf[i] & (BSZ - 1)], 1);
    __syncthreads();
    const int n0 = (k << BSH) + tid;
    if (n0 < N) out_norm[n0] = 1.0f / sqrtf((float)max(cnt[tid], 1));
}

// ---------------- dense compute ----------------

// WT[w][n][k] = (fp16) W_w[k][n] for w = 0..2; plus split-fp16 Wp (hi + residual)
__global__ void convw_kernel(const float* __restrict__ W1, const float* __restrict__ W2,
                             const float* __restrict__ W3, const float* __restrict__ Wp,
                             _Float16* __restrict__ WT,
                             _Float16* __restrict__ Wph, _Float16* __restrict__ Wpr) {
    int i = blockIdx.x * blockDim.x + threadIdx.x;
    if (i < 3 * HDIM * HDIM) {
        int w = i >> 14, r = i & (HDIM * HDIM - 1);
        int nn = r >> 7, k = r & 127;
        const float* W = (w == 0) ? W1 : (w == 1) ? W2 : W3;
        WT[i] = (_Float16)W[k * HDIM + nn];
    } else if (i < 3 * HDIM * HDIM + NCLS * HDIM) {
        int j = i - 3 * HDIM * HDIM;
        float v = Wp[j];
        _Float16 hi = (_Float16)v;
        Wph[j] = hi;
        Wpr[j] = (_Float16)(v - (float)hi);
    }
}

// out[m,:] = fp16( (out_norm[m]*x[m,:]) @ W ) via mfma_f32_16x16x32_f16.
// 128-row block, 2 m-tiles/wave; fp16 LDS staging; IT = float or _Float16.
template <typename IT>
__global__ __launch_bounds__(256) void gemm_mfma_kernel(
        const IT* __restrict__ x, const _Float16* __restrict__ WT,
        const float* __restrict__ out_norm, _Float16* __restrict__ out, int n) {
    __shared__ _Float16 xh[128 * 136];          // 34.8 KB; also epilogue cs
    const int tid = threadIdx.x;
    const int wave = tid >> 6, lane = tid & 63;
    const int quad = lane >> 4, cI = lane & 15;
    const int row0 = blockIdx.x * 128;

    for (int t = tid; t < 128 * 16; t += 256) {
        int r = t >> 4, c8 = t & 15;
        int gr = row0 + r;
        half8 hv = {};
        if (gr < n) {
            float sc = out_norm[gr];
            if constexpr (sizeof(IT) == 2) {
                half8 v = *(const half8*)((const _Float16*)x + (size_t)gr * HDIM + c8 * 8);
                #pragma unroll
                for (int q = 0; q < 8; ++q) hv[q] = (_Float16)((float)v[q] * sc);
            } else {
                const float* xr = (const float*)x + (size_t)gr * HDIM + c8 * 8;
                float4 u = *(const float4*)xr;
                float4 v = *(const float4*)(xr + 4);
                hv[0] = (_Float16)(u.x * sc); hv[1] = (_Float16)(u.y * sc);
                hv[2] = (_Float16)(u.z * sc); hv[3] = (_Float16)(u.w * sc);
                hv[4] = (_Float16)(v.x * sc); hv[5] = (_Float16)(v.y * sc);
                hv[6] = (_Float16)(v.z * sc); hv[7] = (_Float16)(v.w * sc);
            }
        }
        *(half8*)&xh[r * 136 + c8 * 8] = hv;
    }
    __syncthreads();

    half8 afr[2][4];
    #pragma unroll
    for (int i = 0; i < 2; ++i) {
        int mrow = wave * 32 + i * 16 + cI;
        #pragma unroll
        for (int kc = 0; kc < 4; ++kc)
            afr[i][kc] = *(const half8*)&xh[mrow * 136 + kc * 32 + quad * 8];
    }
    __syncthreads();

    f32x4 acc[2][8];
    #pragma unroll
    for (int i = 0; i < 2; ++i)
        #pragma unroll
        for (int nt = 0; nt < 8; ++nt) acc[i][nt] = (f32x4){0.f, 0.f, 0.f, 0.f};

    #pragma unroll
    for (int nt = 0; nt < 8; ++nt) {
        const _Float16* wb = WT + (size_t)(nt * 16 + cI) * HDIM + quad * 8;
        half8 bfr[4];
        #pragma unroll
        for (int kc = 0; kc < 4; ++kc) bfr[kc] = *(const half8*)(wb + kc * 32);
        #pragma unroll
        for (int i = 0; i < 2; ++i)
            #pragma unroll
            for (int kc = 0; kc < 4; ++kc)
                acc[i][nt] = __builtin_amdgcn_mfma_f32_16x16x32_f16(afr[i][kc], bfr[kc], acc[i][nt], 0, 0, 0);
    }

    _Float16 (*cs)[136] = (_Float16(*)[136])xh;
    #pragma unroll
    for (int i = 0; i < 2; ++i)
        #pragma unroll
        for (int nt = 0; nt < 8; ++nt)
            #pragma unroll
            for (int r = 0; r < 4; ++r)
                cs[wave * 32 + i * 16 + quad * 4 + r][nt * 16 + cI] = (_Float16)acc[i][nt][r];
    __syncthreads();

    for (int t = tid; t < 128 * 16; t += 256) {
        int r = t >> 4, c8 = t & 15;
        int gr = row0 + r;
        if (gr < n)
            *(float4*)(out + (size_t)gr * HDIM + c8 * 8) = *(float4*)&cs[r][c8 * 8];
    }
}

// accumulate one 16-B fp16 chunk into 8 fp32 sums
__device__ __forceinline__ void acc16(const float4& r, float* f) {
    const __half2* p = (const __half2*)&r;
    #pragma unroll
    for (int q = 0; q < 4; ++q) {
        float2 g = __half22float2(p[q]);
        f[2 * q]     += g.x;
        f[2 * q + 1] += g.y;
    }
}

// fp16 gather: h[n,:] = relu(in_norm[n]*sum t[col[e],:] + b) — one wave/node,
// 16-lane groups x 4 edges in flight. Output fp16.
__global__ __launch_bounds__(256) void agg_h_kernel(
        const _Float16* __restrict__ t, const int* __restrict__ row_ptr,
        const int* __restrict__ col, const float* __restrict__ in_norm,
        const float* __restrict__ bias, _Float16* __restrict__ h, int n) {
    int node = blockIdx.x * 4 + (threadIdx.x >> 6);
    if (node >= n) return;
    const int lane = threadIdx.x & 63;
    const int eg = lane >> 4;       // edge group 0..3
    const int fq = lane & 15;       // 16-B feature chunk
    const int beg = row_ptr[node], end = row_ptr[node + 1];
    float f0[8] = {}, f1[8] = {}, f2[8] = {}, f3[8] = {};
    for (int e = beg; e < end; e += 64) {
        int cnt = min(64, end - e);
        int ci = (lane < cnt) ? col[e + lane] : 0;
        for (int j = 0; j < cnt; j += 16) {
            int s0 = __shfl(ci, j + eg, 64);
            int s1 = __shfl(ci, j + 4 + eg, 64);
            int s2 = __shfl(ci, j + 8 + eg, 64);
            int s3 = __shfl(ci, j + 12 + eg, 64);
            float4 r0 = {0.f,0.f,0.f,0.f}, r1 = {0.f,0.f,0.f,0.f};
            float4 r2 = {0.f,0.f,0.f,0.f}, r3 = {0.f,0.f,0.f,0.f};
            if (j + eg < cnt)      r0 = ((const float4*)(t + (size_t)s0 * HDIM))[fq];
            if (j + 4 + eg < cnt)  r1 = ((const float4*)(t + (size_t)s1 * HDIM))[fq];
            if (j + 8 + eg < cnt)  r2 = ((const float4*)(t + (size_t)s2 * HDIM))[fq];
            if (j + 12 + eg < cnt) r3 = ((const float4*)(t + (size_t)s3 * HDIM))[fq];
            acc16(r0, f0);
            acc16(r1, f1);
            acc16(r2, f2);
            acc16(r3, f3);
        }
    }
    float f[8];
    #pragma unroll
    for (int q = 0; q < 8; ++q) f[q] = (f0[q] + f1[q]) + (f2[q] + f3[q]);
    #pragma unroll
    for (int q = 0; q < 8; ++q) f[q] += __shfl_xor(f[q], 16, 64);
    #pragma unroll
    for (int q = 0; q < 8; ++q) f[q] += __shfl_xor(f[q], 32, 64);
    if (eg == 0) {
        float inn = in_norm[node];
        float4 b0 = ((const float4*)bias)[2 * fq];
        float4 b1 = ((const float4*)bias)[2 * fq + 1];
        half8 hv;
        hv[0] = (_Float16)fmaxf(f[0] * inn + b0.x, 0.f);
        hv[1] = (_Float16)fmaxf(f[1] * inn + b0.y, 0.f);
        hv[2] = (_Float16)fmaxf(f[2] * inn + b0.z, 0.f);
        hv[3] = (_Float16)fmaxf(f[3] * inn + b0.w, 0.f);
        hv[4] = (_Float16)fmaxf(f[4] * inn + b1.x, 0.f);
        hv[5] = (_Float16)fmaxf(f[5] * inn + b1.y, 0.f);
        hv[6] = (_Float16)fmaxf(f[6] * inn + b1.z, 0.f);
        hv[7] = (_Float16)fmaxf(f[7] * inn + b1.w, 0.f);
        *(half8*)(h + (size_t)node * HDIM + fq * 8) = hv;
    }
}

__global__ void seg_kernel(const float* __restrict__ colsum, const float* __restrict__ Wp,
                           const float* __restrict__ bp, float* __restrict__ segout, float inv_n) {
    int c = threadIdx.x;
    if (c < NCLS) {
        float s = 0.f;
        #pragma unroll 4
        for (int k = 0; k < HDIM; ++k) s = fmaf(colsum[k], Wp[c * HDIM + k], s);
        segout[c] = s * inv_n + bp[c];
    }
}

// CAM via MFMA: CAM[c,n] = dot(Wp[c,:], h3[n,:]).
// A = split-fp16 Wp (3 class-tiles, pad 40->48); B = h3 rows (half8/lane).
// Wave = 64 nodes (4 n-tiles); block = 256 nodes. Fused colsum via per-lane
// partials + 16-lane shuffle reduce + 32 atomics/wave.
__global__ __launch_bounds__(256) void cam_mfma_kernel(
        const _Float16* __restrict__ h, const _Float16* __restrict__ Wph,
        const _Float16* __restrict__ Wpr, float* __restrict__ out,
        float* __restrict__ colsum, int n) {
    const int tid = threadIdx.x;
    const int wave = tid >> 6, lane = tid & 63;
    const int quad = lane >> 4, cI = lane & 15;
    const int n0 = blockIdx.x * 256 + wave * 64;

    // A-frags: class = ct*16 + cI; zero-pad classes >= NCLS
    half8 ah[3][4], ar[3][4];
    #pragma unroll
    for (int ct = 0; ct < 3; ++ct) {
        int cls = ct * 16 + cI;
        bool valid = cls < NCLS;
        int clc = valid ? cls : 0;
        #pragma unroll
        for (int kc = 0; kc < 4; ++kc) {
            half8 z = {};
            half8 vh = *(const half8*)(Wph + clc * HDIM + kc * 32 + quad * 8);
            half8 vr = *(const half8*)(Wpr + clc * HDIM + kc * 32 + quad * 8);
            ah[ct][kc] = valid ? vh : z;
            ar[ct][kc] = valid ? vr : z;
        }
    }

    float csum[4][8] = {};   // [kc][j] per-lane colsum partials

    #pragma unroll
    for (int nt = 0; nt < 4; ++nt) {
        const int node = n0 + nt * 16 + cI;
        const bool nv = node < n;
        half8 b[4];
        #pragma unroll
        for (int kc = 0; kc < 4; ++kc) {
            half8 z = {};
            half8 v = z;
            if (nv) v = *(const half8*)(h + (size_t)node * HDIM + kc * 32 + quad * 8);
            b[kc] = v;
            #pragma unroll
            for (int j = 0; j < 8; ++j) csum[kc][j] += (float)v[j];
        }
        #pragma unroll
        for (int ct = 0; ct < 3; ++ct) {
            f32x4 acc = (f32x4){0.f, 0.f, 0.f, 0.f};
            #pragma unroll
            for (int kc = 0; kc < 4; ++kc)
                acc = __builtin_amdgcn_mfma_f32_16x16x32_f16(ah[ct][kc], b[kc], acc, 0, 0, 0);
            #pragma unroll
            for (int kc = 0; kc < 4; ++kc)
                acc = __builtin_amdgcn_mfma_f32_16x16x32_f16(ar[ct][kc], b[kc], acc, 0, 0, 0);
            // D: col = cI (node), row = quad*4 + r (class within tile)
            #pragma unroll
            for (int r = 0; r < 4; ++r) {
                int cls = ct * 16 + quad * 4 + r;
                if (cls < NCLS && nv)
                    out[(size_t)cls * n + node] = acc[r];
            }
        }
    }

    // colsum: lanes sharing a quad hold the same k-set for different nodes
    #pragma unroll
    for (int kc = 0; kc < 4; ++kc)
        #pragma unroll
        for (int j = 0; j < 8; ++j) {
            float v = csum[kc][j];
            v += __shfl_xor(v, 1, 64);
            v += __shfl_xor(v, 2, 64);
            v += __shfl_xor(v, 4, 64);
            v += __shfl_xor(v, 8, 64);
            if (cI == 0) atomicAdd(&colsum[kc * 32 + quad * 8 + j], v);
        }
}

// ---------------- launch ----------------

extern "C" void kernel_launch(void* const* d_in, const int* in_sizes, int n_in,
                              void* d_out, int out_size, void* d_ws, size_t ws_size,
                              hipStream_t stream) {
    const float* features = (const float*)d_in[0];
    const float* W1 = (const float*)d_in[1];
    const float* b1 = (const float*)d_in[2];
    const float* W2 = (const float*)d_in[3];
    const float* b2 = (const float*)d_in[4];
    const float* W3 = (const float*)d_in[5];
    const float* b3 = (const float*)d_in[6];
    const float* Wp = (const float*)d_in[7];
    const float* bp = (const float*)d_in[8];
    const int*   src = (const int*)d_in[9];
    const int*   dst = (const int*)d_in[10];

    const int N = in_sizes[0] / HDIM;
    const int E = in_sizes[9];
    const int K = (N + BSZ - 1) >> BSH;           // buckets (<= KMAX)
    float* out = (float*)d_out;

    // workspace carve-up
    char* ws = (char*)d_ws;
    size_t off = 0;
    int* bcnt   = (int*)(ws + off); off += KMAX * 4;
    int* sbcnt  = (int*)(ws + off); off += KMAX * 4;
    int* bcur   = (int*)(ws + off); off += KMAX * 4;
    int* scur   = (int*)(ws + off); off += KMAX * 4;
    float* colsum = (float*)(ws + off); off += 128 * 4;
    int* bbase  = (int*)(ws + off); off += (KMAX + 1) * 4;
    int* sbase  = (int*)(ws + off); off += (KMAX + 1) * 4;
    int* row_ptr = (int*)(ws + off); off += ((size_t)N + 1) * 4; off = (off + 15) & ~(size_t)15;
    int* col_idx = (int*)(ws + off); off += (size_t)E * 4; off = (off + 15) & ~(size_t)15;
    float* out_norm = (float*)(ws + off); off += (size_t)N * 4;
    float* in_norm  = (float*)(ws + off); off += (size_t)N * 4; off = (off + 255) & ~(size_t)255;
    _Float16* WT  = (_Float16*)(ws + off); off += 3 * HDIM * HDIM * 2;
    _Float16* Wph = (_Float16*)(ws + off); off += NCLS * HDIM * 2;
    _Float16* Wpr = (_Float16*)(ws + off); off += NCLS * HDIM * 2; off = (off + 255) & ~(size_t)255;
    _Float16* Bh  = (_Float16*)(ws + off); off += (size_t)N * HDIM * 2; off = (off + 255) & ~(size_t)255;
    _Float16* F0h = (_Float16*)(ws + off); off += (size_t)N * HDIM * 2; off = (off + 255) & ~(size_t)255;
    (void)ws_size; (void)n_in; (void)out_size;

    // bucket scratch aliases F0h (consumed by build_csr/outdeg before agg1 writes F0h)
    int2* dbuf = (int2*)F0h;                          // E*8 B
    int*  sbuf = (int*)((char*)F0h + (size_t)E * 8);  // E*4 B

    const int NB = (E + EPB - 1) / EPB;

    const int nzero = 4 * KMAX + 128;
    zero_kernel<<<(nzero + 255) / 256, 256, 0, stream>>>((int*)ws, nzero);
    bucket_count_kernel<<<NB, 256, 0, stream>>>(src, dst, bcnt, sbcnt, K, E);
    bucket_scan_kernel<<<1, 64, 0, stream>>>(bcnt, sbcnt, bbase, sbase, K);
    bucket_scatter_kernel<<<NB, 256, 0, stream>>>(src, dst, bbase, sbase, bcur, scur,
                                                  dbuf, sbuf, K, E);
    build_csr_kernel<<<K, 256, 0, stream>>>(dbuf, bbase, row_ptr, in_norm, col_idx, N, K, E);
    outdeg_kernel<<<K, 256, 0, stream>>>(sbuf, sbase, out_norm, N);

    const int nconv = 3 * HDIM * HDIM + NCLS * HDIM;
    convw_kernel<<<(nconv + 255) / 256, 256, 0, stream>>>(W1, W2, W3, Wp, WT, Wph, Wpr);

    const int gemm_blocks = (N + 127) / 128;
    const int agg_blocks  = (N + 3) / 4;

    // layer 1
    gemm_mfma_kernel<float><<<gemm_blocks, 256, 0, stream>>>(features, WT, out_norm, Bh, N);
    agg_h_kernel<<<agg_blocks, 256, 0, stream>>>(Bh, row_ptr, col_idx, in_norm, b1, F0h, N);
    // layer 2
    gemm_mfma_kernel<_Float16><<<gemm_blocks, 256, 0, stream>>>(F0h, WT + HDIM * HDIM, out_norm, Bh, N);
    agg_h_kernel<<<agg_blocks, 256, 0, stream>>>(Bh, row_ptr, col_idx, in_norm, b2, F0h, N);
    // layer 3 (h3 fp16 -> F0h)
    gemm_mfma_kernel<_Float16><<<gemm_blocks, 256, 0, stream>>>(F0h, WT + 2 * HDIM * HDIM, out_norm, Bh, N);
    agg_h_kernel<<<agg_blocks, 256, 0, stream>>>(Bh, row_ptr, col_idx, in_norm, b3, F0h, N);

    // head: cam (MFMA, fused colsum) then seg
    cam_mfma_kernel<<<(N + 255) / 256, 256, 0, stream>>>(F0h, Wph, Wpr, out + NCLS, colsum, N);
    seg_kernel<<<1, 64, 0, stream>>>(colsum, Wp, bp, out, 1.0f / (float)N);
}

// Round 11
// 476.710 us; speedup vs baseline: 1.6639x; 1.6639x over previous
//
#include <hip/hip_runtime.h>
#include <hip/hip_bf16.h>
#include <hip/hip_fp16.h>

// GCN: 3 layers of  h = relu(in_norm * A_pull( (out_norm*x) @ W ) + b)
// then seg_output = (mean_n h3) @ Wp^T + bp  and  CAM = Wp @ h3^T.
// Preprocessing: bucketed CSR (256-node buckets), no scattered global atomics
// (gfx950 atomics write through L2 at ~0.7 TB/s of 32B sectors [R1/R2/R4]).
// agg is memory-bound at its FETCH floor [R6/R7]. All h tensors fp16.
// CAM = MFMA GEMM, h-tile staged in LDS, Wp (split-fp16 hi+residual -> exact)
// loaded per class-tile: ~60 live VGPRs. [R10 failed: 96-VGPR A-frag cache
// spilled to scratch -> 349us; R8 LDS-bound; R9 SMEM-latency-bound.]

#define HDIM 128
#define NCLS 40
#define BSH 8
#define BSZ 256          // nodes per bucket
#define KMAX 512
#define EPB 4096         // edges per scatter/count block
#define CSTRIDE 140      // cam LDS row stride (fp16): 70 dwords, spreads banks

typedef _Float16 half8 __attribute__((ext_vector_type(8)));
typedef float f32x4 __attribute__((ext_vector_type(4)));

// ---------------- graph preprocessing ----------------

__global__ void zero_kernel(int* __restrict__ p, int n) {
    int i = blockIdx.x * blockDim.x + threadIdx.x;
    if (i < n) p[i] = 0;
}

// per-block LDS bucket histograms (dst and src), merged with contiguous atomics
__global__ __launch_bounds__(256) void bucket_count_kernel(
        const int* __restrict__ src, const int* __restrict__ dst,
        int* __restrict__ bcnt, int* __restrict__ sbcnt, int K, int E) {
    __shared__ int lc[KMAX], ls[KMAX];
    const int tid = threadIdx.x;
    lc[tid] = 0; lc[tid + 256] = 0; ls[tid] = 0; ls[tid + 256] = 0;
    __syncthreads();
    const int base = blockIdx.x * EPB;
    const int lim = min(EPB, E - base);
    for (int i = tid; i < lim; i += 256) {
        atomicAdd(&lc[dst[base + i] >> BSH], 1);
        atomicAdd(&ls[src[base + i] >> BSH], 1);
    }
    __syncthreads();
    for (int t = tid; t < K; t += 256) {
        if (lc[t]) atomicAdd(&bcnt[t], lc[t]);
        if (ls[t]) atomicAdd(&sbcnt[t], ls[t]);
    }
}

// one wave: sequential 64-chunk exclusive scan of both arrays (K <= KMAX)
__global__ void bucket_scan_kernel(const int* __restrict__ a, const int* __restrict__ b,
                                   int* __restrict__ abase, int* __restrict__ bbase, int K) {
    const int lane = threadIdx.x;   // blockDim = 64
    int ca = 0, cb = 0;
    for (int base = 0; base < K; base += 64) {
        int va = (base + lane < K) ? a[base + lane] : 0;
        int vb = (base + lane < K) ? b[base + lane] : 0;
        int ia = va, ib = vb;
        #pragma unroll
        for (int d = 1; d < 64; d <<= 1) {
            int oa = __shfl_up(ia, d, 64);
            int ob = __shfl_up(ib, d, 64);
            if (lane >= d) { ia += oa; ib += ob; }
        }
        if (base + lane < K) { abase[base + lane] = ca + ia - va; bbase[base + lane] = cb + ib - vb; }
        ca += __shfl(ia, 63, 64);
        cb += __shfl(ib, 63, 64);
    }
    if (lane == 0) { abase[K] = ca; bbase[K] = cb; }
}

// re-count in LDS, reserve contiguous runs, write bucketed records
__global__ __launch_bounds__(256) void bucket_scatter_kernel(
        const int* __restrict__ src, const int* __restrict__ dst,
        const int* __restrict__ bbase, const int* __restrict__ sbase,
        int* __restrict__ bcur, int* __restrict__ scur,
        int2* __restrict__ dbuf, int* __restrict__ sbuf, int K, int E) {
    __shared__ int lc[KMAX], lb[KMAX], ls[KMAX], lsb[KMAX];
    const int tid = threadIdx.x;
    lc[tid] = 0; lc[tid + 256] = 0; ls[tid] = 0; ls[tid + 256] = 0;
    __syncthreads();
    const int base = blockIdx.x * EPB;
    const int lim = min(EPB, E - base);
    for (int i = tid; i < lim; i += 256) {
        atomicAdd(&lc[dst[base + i] >> BSH], 1);
        atomicAdd(&ls[src[base + i] >> BSH], 1);
    }
    __syncthreads();
    for (int t = tid; t < K; t += 256) {
        lb[t]  = bbase[t] + (lc[t] ? atomicAdd(&bcur[t], lc[t]) : 0);
        lsb[t] = sbase[t] + (ls[t] ? atomicAdd(&scur[t], ls[t]) : 0);
    }
    __syncthreads();
    lc[tid] = 0; lc[tid + 256] = 0; ls[tid] = 0; ls[tid + 256] = 0;
    __syncthreads();
    for (int i = tid; i < lim; i += 256) {
        int d = dst[base + i], s = src[base + i];
        int kd = d >> BSH, ks = s >> BSH;
        int r = atomicAdd(&lc[kd], 1);
        dbuf[lb[kd] + r] = make_int2(d, s);
        int r2 = atomicAdd(&ls[ks], 1);
        sbuf[lsb[ks] + r2] = s;
    }
}

// one block per dst-bucket: histogram -> scan -> row_ptr/in_norm -> ranks -> col
__global__ __launch_bounds__(256) void build_csr_kernel(
        const int2* __restrict__ dbuf, const int* __restrict__ bbase,
        int* __restrict__ row_ptr, float* __restrict__ in_norm,
        int* __restrict__ col, int N, int K, int E) {
    __shared__ int cnt[BSZ], lsc[BSZ];
    __shared__ int wsum[4];
    const int k = blockIdx.x, tid = threadIdx.x;
    const int node0 = k << BSH;
    const int beg = bbase[k], end = bbase[k + 1];
    cnt[tid] = 0;
    __syncthreads();
    for (int i = beg + tid; i < end; i += 256)
        atomicAdd(&cnt[dbuf[i].x & (BSZ - 1)], 1);
    __syncthreads();
    const int c0 = cnt[tid];
    int incl = c0;
    const int lane = tid & 63, w = tid >> 6;
    #pragma unroll
    for (int d = 1; d < 64; d <<= 1) {
        int o = __shfl_up(incl, d, 64);
        if (lane >= d) incl += o;
    }
    if (lane == 63) wsum[w] = incl;
    __syncthreads();
    int off = 0;
    for (int j = 0; j < w; ++j) off += wsum[j];
    const int excl = off + incl - c0;
    lsc[tid] = excl;
    const int node = node0 + tid;
    if (node < N) { row_ptr[node] = beg + excl; in_norm[node] = 1.0f / sqrtf((float)max(c0, 1)); }
    if (k == K - 1 && tid == 0) row_ptr[N] = E;
    __syncthreads();
    cnt[tid] = 0;
    __syncthreads();
    for (int i = beg + tid; i < end; i += 256) {
        int2 e = dbuf[i];
        int local = e.x & (BSZ - 1);
        int r = atomicAdd(&cnt[local], 1);
        col[beg + lsc[local] + r] = e.y;
    }
}

// one block per src-bucket: histogram -> out_norm
__global__ __launch_bounds__(256) void outdeg_kernel(
        const int* __restrict__ sbuf, const int* __restrict__ sbase,
        float* __restrict__ out_norm, int N) {
    __shared__ int cnt[BSZ];
    const int k = blockIdx.x, tid = threadIdx.x;
    const int beg = sbase[k], end = sbase[k + 1];
    cnt[tid] = 0;
    __syncthreads();
    for (int i = beg + tid; i < end; i += 256)
        atomicAdd(&cnt[sbuf[i] & (BSZ - 1)], 1);
    __syncthreads();
    const int n0 = (k << BSH) + tid;
    if (n0 < N) out_norm[n0] = 1.0f / sqrtf((float)max(cnt[tid], 1));
}

// ---------------- dense compute ----------------

// WT[w][n][k] = (fp16) W_w[k][n] for w = 0..2; plus split-fp16 Wp (hi + residual)
__global__ void convw_kernel(const float* __restrict__ W1, const float* __restrict__ W2,
                             const float* __restrict__ W3, const float* __restrict__ Wp,
                             _Float16* __restrict__ WT,
                             _Float16* __restrict__ Wph, _Float16* __restrict__ Wpr) {
    int i = blockIdx.x * blockDim.x + threadIdx.x;
    if (i < 3 * HDIM * HDIM) {
        int w = i >> 14, r = i & (HDIM * HDIM - 1);
        int nn = r >> 7, k = r & 127;
        const float* W = (w == 0) ? W1 : (w == 1) ? W2 : W3;
        WT[i] = (_Float16)W[k * HDIM + nn];
    } else if (i < 3 * HDIM * HDIM + NCLS * HDIM) {
        int j = i - 3 * HDIM * HDIM;
        float v = Wp[j];
        _Float16 hi = (_Float16)v;
        Wph[j] = hi;
        Wpr[j] = (_Float16)(v - (float)hi);
    }
}

// out[m,:] = fp16( (out_norm[m]*x[m,:]) @ W ) via mfma_f32_16x16x32_f16.
// 128-row block, 2 m-tiles/wave; fp16 LDS staging; IT = float or _Float16.
template <typename IT>
__global__ __launch_bounds__(256) void gemm_mfma_kernel(
        const IT* __restrict__ x, const _Float16* __restrict__ WT,
        const float* __restrict__ out_norm, _Float16* __restrict__ out, int n) {
    __shared__ _Float16 xh[128 * 136];          // 34.8 KB; also epilogue cs
    const int tid = threadIdx.x;
    const int wave = tid >> 6, lane = tid & 63;
    const int quad = lane >> 4, cI = lane & 15;
    const int row0 = blockIdx.x * 128;

    for (int t = tid; t < 128 * 16; t += 256) {
        int r = t >> 4, c8 = t & 15;
        int gr = row0 + r;
        half8 hv = {};
        if (gr < n) {
            float sc = out_norm[gr];
            if constexpr (sizeof(IT) == 2) {
                half8 v = *(const half8*)((const _Float16*)x + (size_t)gr * HDIM + c8 * 8);
                #pragma unroll
                for (int q = 0; q < 8; ++q) hv[q] = (_Float16)((float)v[q] * sc);
            } else {
                const float* xr = (const float*)x + (size_t)gr * HDIM + c8 * 8;
                float4 u = *(const float4*)xr;
                float4 v = *(const float4*)(xr + 4);
                hv[0] = (_Float16)(u.x * sc); hv[1] = (_Float16)(u.y * sc);
                hv[2] = (_Float16)(u.z * sc); hv[3] = (_Float16)(u.w * sc);
                hv[4] = (_Float16)(v.x * sc); hv[5] = (_Float16)(v.y * sc);
                hv[6] = (_Float16)(v.z * sc); hv[7] = (_Float16)(v.w * sc);
            }
        }
        *(half8*)&xh[r * 136 + c8 * 8] = hv;
    }
    __syncthreads();

    half8 afr[2][4];
    #pragma unroll
    for (int i = 0; i < 2; ++i) {
        int mrow = wave * 32 + i * 16 + cI;
        #pragma unroll
        for (int kc = 0; kc < 4; ++kc)
            afr[i][kc] = *(const half8*)&xh[mrow * 136 + kc * 32 + quad * 8];
    }
    __syncthreads();

    f32x4 acc[2][8];
    #pragma unroll
    for (int i = 0; i < 2; ++i)
        #pragma unroll
        for (int nt = 0; nt < 8; ++nt) acc[i][nt] = (f32x4){0.f, 0.f, 0.f, 0.f};

    #pragma unroll
    for (int nt = 0; nt < 8; ++nt) {
        const _Float16* wb = WT + (size_t)(nt * 16 + cI) * HDIM + quad * 8;
        half8 bfr[4];
        #pragma unroll
        for (int kc = 0; kc < 4; ++kc) bfr[kc] = *(const half8*)(wb + kc * 32);
        #pragma unroll
        for (int i = 0; i < 2; ++i)
            #pragma unroll
            for (int kc = 0; kc < 4; ++kc)
                acc[i][nt] = __builtin_amdgcn_mfma_f32_16x16x32_f16(afr[i][kc], bfr[kc], acc[i][nt], 0, 0, 0);
    }

    _Float16 (*cs)[136] = (_Float16(*)[136])xh;
    #pragma unroll
    for (int i = 0; i < 2; ++i)
        #pragma unroll
        for (int nt = 0; nt < 8; ++nt)
            #pragma unroll
            for (int r = 0; r < 4; ++r)
                cs[wave * 32 + i * 16 + quad * 4 + r][nt * 16 + cI] = (_Float16)acc[i][nt][r];
    __syncthreads();

    for (int t = tid; t < 128 * 16; t += 256) {
        int r = t >> 4, c8 = t & 15;
        int gr = row0 + r;
        if (gr < n)
            *(float4*)(out + (size_t)gr * HDIM + c8 * 8) = *(float4*)&cs[r][c8 * 8];
    }
}

// accumulate one 16-B fp16 chunk into 8 fp32 sums
__device__ __forceinline__ void acc16(const float4& r, float* f) {
    const __half2* p = (const __half2*)&r;
    #pragma unroll
    for (int q = 0; q < 4; ++q) {
        float2 g = __half22float2(p[q]);
        f[2 * q]     += g.x;
        f[2 * q + 1] += g.y;
    }
}

// fp16 gather: h[n,:] = relu(in_norm[n]*sum t[col[e],:] + b) — one wave/node,
// 16-lane groups x 4 edges in flight. Output fp16.
__global__ __launch_bounds__(256) void agg_h_kernel(
        const _Float16* __restrict__ t, const int* __restrict__ row_ptr,
        const int* __restrict__ col, const float* __restrict__ in_norm,
        const float* __restrict__ bias, _Float16* __restrict__ h, int n) {
    int node = blockIdx.x * 4 + (threadIdx.x >> 6);
    if (node >= n) return;
    const int lane = threadIdx.x & 63;
    const int eg = lane >> 4;       // edge group 0..3
    const int fq = lane & 15;       // 16-B feature chunk
    const int beg = row_ptr[node], end = row_ptr[node + 1];
    float f0[8] = {}, f1[8] = {}, f2[8] = {}, f3[8] = {};
    for (int e = beg; e < end; e += 64) {
        int cnt = min(64, end - e);
        int ci = (lane < cnt) ? col[e + lane] : 0;
        for (int j = 0; j < cnt; j += 16) {
            int s0 = __shfl(ci, j + eg, 64);
            int s1 = __shfl(ci, j + 4 + eg, 64);
            int s2 = __shfl(ci, j + 8 + eg, 64);
            int s3 = __shfl(ci, j + 12 + eg, 64);
            float4 r0 = {0.f,0.f,0.f,0.f}, r1 = {0.f,0.f,0.f,0.f};
            float4 r2 = {0.f,0.f,0.f,0.f}, r3 = {0.f,0.f,0.f,0.f};
            if (j + eg < cnt)      r0 = ((const float4*)(t + (size_t)s0 * HDIM))[fq];
            if (j + 4 + eg < cnt)  r1 = ((const float4*)(t + (size_t)s1 * HDIM))[fq];
            if (j + 8 + eg < cnt)  r2 = ((const float4*)(t + (size_t)s2 * HDIM))[fq];
            if (j + 12 + eg < cnt) r3 = ((const float4*)(t + (size_t)s3 * HDIM))[fq];
            acc16(r0, f0);
            acc16(r1, f1);
            acc16(r2, f2);
            acc16(r3, f3);
        }
    }
    float f[8];
    #pragma unroll
    for (int q = 0; q < 8; ++q) f[q] = (f0[q] + f1[q]) + (f2[q] + f3[q]);
    #pragma unroll
    for (int q = 0; q < 8; ++q) f[q] += __shfl_xor(f[q], 16, 64);
    #pragma unroll
    for (int q = 0; q < 8; ++q) f[q] += __shfl_xor(f[q], 32, 64);
    if (eg == 0) {
        float inn = in_norm[node];
        float4 b0 = ((const float4*)bias)[2 * fq];
        float4 b1 = ((const float4*)bias)[2 * fq + 1];
        half8 hv;
        hv[0] = (_Float16)fmaxf(f[0] * inn + b0.x, 0.f);
        hv[1] = (_Float16)fmaxf(f[1] * inn + b0.y, 0.f);
        hv[2] = (_Float16)fmaxf(f[2] * inn + b0.z, 0.f);
        hv[3] = (_Float16)fmaxf(f[3] * inn + b0.w, 0.f);
        hv[4] = (_Float16)fmaxf(f[4] * inn + b1.x, 0.f);
        hv[5] = (_Float16)fmaxf(f[5] * inn + b1.y, 0.f);
        hv[6] = (_Float16)fmaxf(f[6] * inn + b1.z, 0.f);
        hv[7] = (_Float16)fmaxf(f[7] * inn + b1.w, 0.f);
        *(half8*)(h + (size_t)node * HDIM + fq * 8) = hv;
    }
}

__global__ void seg_kernel(const float* __restrict__ colsum, const float* __restrict__ Wp,
                           const float* __restrict__ bp, float* __restrict__ segout, float inv_n) {
    int c = threadIdx.x;
    if (c < NCLS) {
        float s = 0.f;
        #pragma unroll 4
        for (int k = 0; k < HDIM; ++k) s = fmaf(colsum[k], Wp[c * HDIM + k], s);
        segout[c] = s * inv_n + bp[c];
    }
}

// CAM via MFMA: CAM[c,n] = dot(Wp[c,:], h3[n,:]).
// Block = 128 nodes staged in LDS (35 KB); wave = 32 nodes (2 n-tiles).
// Per class-tile ct: load A (Wp hi+res, 32 VGPRs live), B from LDS, store acc
// immediately -> ~60 live VGPRs, no spill [R10 lesson]. Fused colsum from LDS.
__global__ __launch_bounds__(256) void cam_mfma_kernel(
        const _Float16* __restrict__ h, const _Float16* __restrict__ Wph,
        const _Float16* __restrict__ Wpr, float* __restrict__ out,
        float* __restrict__ colsum, int n) {
    __shared__ _Float16 hs[128 * CSTRIDE];      // 35 KB
    const int tid = threadIdx.x;
    const int wave = tid >> 6, lane = tid & 63;
    const int quad = lane >> 4, cI = lane & 15;
    const int n0 = blockIdx.x * 128;

    // stage h tile (zero-padded past n), coalesced half8
    for (int t = tid; t < 128 * 16; t += 256) {
        int r = t >> 4, c8 = t & 15;
        int gr = n0 + r;
        half8 v = {};
        if (gr < n) v = *(const half8*)(h + (size_t)gr * HDIM + c8 * 8);
        *(half8*)&hs[r * CSTRIDE + c8 * 8] = v;
    }
    __syncthreads();

    #pragma unroll
    for (int ct = 0; ct < 3; ++ct) {
        // A-frags for this class tile only (zero-pad classes >= NCLS)
        const int cls = ct * 16 + cI;
        const bool av = cls < NCLS;
        const int clc = av ? cls : 0;
        half8 ah[4], ar[4];
        #pragma unroll
        for (int kc = 0; kc < 4; ++kc) {
            half8 z = {};
            half8 vh = *(const half8*)(Wph + clc * HDIM + kc * 32 + quad * 8);
            half8 vr = *(const half8*)(Wpr + clc * HDIM + kc * 32 + quad * 8);
            ah[kc] = av ? vh : z;
            ar[kc] = av ? vr : z;
        }
        #pragma unroll
        for (int t = 0; t < 2; ++t) {
            const int ln = wave * 32 + t * 16 + cI;   // local node (B col)
            f32x4 acc = (f32x4){0.f, 0.f, 0.f, 0.f};
            #pragma unroll
            for (int kc = 0; kc < 4; ++kc) {
                half8 b = *(const half8*)&hs[ln * CSTRIDE + kc * 32 + quad * 8];
                acc = __builtin_amdgcn_mfma_f32_16x16x32_f16(ah[kc], b, acc, 0, 0, 0);
                acc = __builtin_amdgcn_mfma_f32_16x16x32_f16(ar[kc], b, acc, 0, 0, 0);
            }
            const int node = n0 + ln;
            // D: col = cI (node), row = quad*4 + r (class within tile)
            #pragma unroll
            for (int r = 0; r < 4; ++r) {
                int c2 = ct * 16 + quad * 4 + r;
                if (c2 < NCLS && node < n)
                    out[(size_t)c2 * n + node] = acc[r];
            }
        }
    }

    // fused colsum from LDS (rows past n are zeros); staging sync covers reads
    if (tid < HDIM) {
        float s = 0.f;
        for (int r = 0; r < 128; ++r) s += (float)hs[r * CSTRIDE + tid];
        atomicAdd(&colsum[tid], s);
    }
}

// ---------------- launch ----------------

extern "C" void kernel_launch(void* const* d_in, const int* in_sizes, int n_in,
                              void* d_out, int out_size, void* d_ws, size_t ws_size,
                              hipStream_t stream) {
    const float* features = (const float*)d_in[0];
    const float* W1 = (const float*)d_in[1];
    const float* b1 = (const float*)d_in[2];
    const float* W2 = (const float*)d_in[3];
    const float* b2 = (const float*)d_in[4];
    const float* W3 = (const float*)d_in[5];
    const float* b3 = (const float*)d_in[6];
    const float* Wp = (const float*)d_in[7];
    const float* bp = (const float*)d_in[8];
    const int*   src = (const int*)d_in[9];
    const int*   dst = (const int*)d_in[10];

    const int N = in_sizes[0] / HDIM;
    const int E = in_sizes[9];
    const int K = (N + BSZ - 1) >> BSH;           // buckets (<= KMAX)
    float* out = (float*)d_out;

    // workspace carve-up
    char* ws = (char*)d_ws;
    size_t off = 0;
    int* bcnt   = (int*)(ws + off); off += KMAX * 4;
    int* sbcnt  = (int*)(ws + off); off += KMAX * 4;
    int* bcur   = (int*)(ws + off); off += KMAX * 4;
    int* scur   = (int*)(ws + off); off += KMAX * 4;
    float* colsum = (float*)(ws + off); off += 128 * 4;
    int* bbase  = (int*)(ws + off); off += (KMAX + 1) * 4;
    int* sbase  = (int*)(ws + off); off += (KMAX + 1) * 4;
    int* row_ptr = (int*)(ws + off); off += ((size_t)N + 1) * 4; off = (off + 15) & ~(size_t)15;
    int* col_idx = (int*)(ws + off); off += (size_t)E * 4; off = (off + 15) & ~(size_t)15;
    float* out_norm = (float*)(ws + off); off += (size_t)N * 4;
    float* in_norm  = (float*)(ws + off); off += (size_t)N * 4; off = (off + 255) & ~(size_t)255;
    _Float16* WT  = (_Float16*)(ws + off); off += 3 * HDIM * HDIM * 2;
    _Float16* Wph = (_Float16*)(ws + off); off += NCLS * HDIM * 2;
    _Float16* Wpr = (_Float16*)(ws + off); off += NCLS * HDIM * 2; off = (off + 255) & ~(size_t)255;
    _Float16* Bh  = (_Float16*)(ws + off); off += (size_t)N * HDIM * 2; off = (off + 255) & ~(size_t)255;
    _Float16* F0h = (_Float16*)(ws + off); off += (size_t)N * HDIM * 2; off = (off + 255) & ~(size_t)255;
    (void)ws_size; (void)n_in; (void)out_size;

    // bucket scratch aliases F0h (consumed by build_csr/outdeg before agg1 writes F0h)
    int2* dbuf = (int2*)F0h;                          // E*8 B
    int*  sbuf = (int*)((char*)F0h + (size_t)E * 8);  // E*4 B

    const int NB = (E + EPB - 1) / EPB;

    const int nzero = 4 * KMAX + 128;
    zero_kernel<<<(nzero + 255) / 256, 256, 0, stream>>>((int*)ws, nzero);
    bucket_count_kernel<<<NB, 256, 0, stream>>>(src, dst, bcnt, sbcnt, K, E);
    bucket_scan_kernel<<<1, 64, 0, stream>>>(bcnt, sbcnt, bbase, sbase, K);
    bucket_scatter_kernel<<<NB, 256, 0, stream>>>(src, dst, bbase, sbase, bcur, scur,
                                                  dbuf, sbuf, K, E);
    build_csr_kernel<<<K, 256, 0, stream>>>(dbuf, bbase, row_ptr, in_norm, col_idx, N, K, E);
    outdeg_kernel<<<K, 256, 0, stream>>>(sbuf, sbase, out_norm, N);

    const int nconv = 3 * HDIM * HDIM + NCLS * HDIM;
    convw_kernel<<<(nconv + 255) / 256, 256, 0, stream>>>(W1, W2, W3, Wp, WT, Wph, Wpr);

    const int gemm_blocks = (N + 127) / 128;
    const int agg_blocks  = (N + 3) / 4;

    // layer 1
    gemm_mfma_kernel<float><<<gemm_blocks, 256, 0, stream>>>(features, WT, out_norm, Bh, N);
    agg_h_kernel<<<agg_blocks, 256, 0, stream>>>(Bh, row_ptr, col_idx, in_norm, b1, F0h, N);
    // layer 2
    gemm_mfma_kernel<_Float16><<<gemm_blocks, 256, 0, stream>>>(F0h, WT + HDIM * HDIM, out_norm, Bh, N);
    agg_h_kernel<<<agg_blocks, 256, 0, stream>>>(Bh, row_ptr, col_idx, in_norm, b2, F0h, N);
    // layer 3 (h3 fp16 -> F0h)
    gemm_mfma_kernel<_Float16><<<gemm_blocks, 256, 0, stream>>>(F0h, WT + 2 * HDIM * HDIM, out_norm, Bh, N);
    agg_h_kernel<<<agg_blocks, 256, 0, stream>>>(Bh, row_ptr, col_idx, in_norm, b3, F0h, N);

    // head: cam (MFMA, fused colsum) then seg
    cam_mfma_kernel<<<(N + 127) / 128, 256, 0, stream>>>(F0h, Wph, Wpr, out + NCLS, colsum, N);
    seg_kernel<<<1, 64, 0, stream>>>(colsum, Wp, bp, out, 1.0f / (float)N);
}

// Round 12
// 463.411 us; speedup vs baseline: 1.7117x; 1.0287x over previous
//
#include <hip/hip_runtime.h>
#include <hip/hip_bf16.h>
#include <hip/hip_fp16.h>

// GCN: 3 layers of  h = relu(in_norm * A_pull( (out_norm*x) @ W ) + b)
// then seg_output = (mean_n h3) @ Wp^T + bp  and  CAM = Wp @ h3^T.
// Preprocessing (R12 streamlined): one count+rank pass (LDS bucket histograms,
// per-edge packed ranks), base-table scans, pure-streaming scatter (4B packed
// dst-records), fused csr+outdeg+convw. No scattered global atomics anywhere
// (gfx950 atomics write through L2 at ~0.7 TB/s of 32B sectors [R1/R2/R4]).
// agg is at its FETCH floor: 8 XCDs x ~86K unique 256B rows ~ 180MB at the
// ~3.5 TB/s L3->L2 random-fill ceiling => ~59us/layer [R6/R7/R11].
// All h tensors fp16. CAM = MFMA GEMM (split-fp16 Wp, exact), ~60 live VGPRs
// [R10: register-cached A spilled; R11 fixed].

#define HDIM 128
#define NCLS 40
#define BSH 8
#define BSZ 256          // nodes per bucket
#define KMAX 512
#define NBMAX 512
#define EPB 4096         // edges per count/scatter block
#define CSTRIDE 140      // cam LDS row stride (fp16)

typedef _Float16 half8 __attribute__((ext_vector_type(8)));
typedef float f32x4 __attribute__((ext_vector_type(4)));

// ---------------- graph preprocessing ----------------

__global__ void zero_kernel(int* __restrict__ p, int n) {
    int i = blockIdx.x * blockDim.x + threadIdx.x;
    if (i < n) p[i] = 0;
}

// One pass: LDS bucket histograms (dst+src), per-edge packed ranks,
// per-(bucket,block) count tables (k-major), global bucket totals.
__global__ __launch_bounds__(256) void count_rank_kernel(
        const int* __restrict__ src, const int* __restrict__ dst,
        int* __restrict__ bcnt, int* __restrict__ sbcnt,
        unsigned* __restrict__ rank, int* __restrict__ cntD, int* __restrict__ cntS,
        int K, int E) {
    __shared__ int lc[KMAX], ls[KMAX];
    const int tid = threadIdx.x;
    lc[tid] = 0; lc[tid + 256] = 0; ls[tid] = 0; ls[tid + 256] = 0;
    __syncthreads();
    const int base = blockIdx.x * EPB;
    const int lim = min(EPB, E - base);
    for (int i = tid; i < lim; i += 256) {
        int kd = dst[base + i] >> BSH, ks = src[base + i] >> BSH;
        unsigned rd = (unsigned)atomicAdd(&lc[kd], 1);
        unsigned rs = (unsigned)atomicAdd(&ls[ks], 1);
        rank[base + i] = rd | (rs << 16);
    }
    __syncthreads();
    for (int t = tid; t < K; t += 256) {
        cntD[t * NBMAX + blockIdx.x] = lc[t];
        cntS[t * NBMAX + blockIdx.x] = ls[t];
        if (lc[t]) atomicAdd(&bcnt[t], lc[t]);
        if (ls[t]) atomicAdd(&sbcnt[t], ls[t]);
    }
}

// one wave: exclusive scan of both bucket-total arrays (K <= KMAX)
__global__ void bucket_scan_kernel(const int* __restrict__ a, const int* __restrict__ b,
                                   int* __restrict__ abase, int* __restrict__ bbase, int K) {
    const int lane = threadIdx.x;   // blockDim = 64
    int ca = 0, cb = 0;
    for (int base = 0; base < K; base += 64) {
        int va = (base + lane < K) ? a[base + lane] : 0;
        int vb = (base + lane < K) ? b[base + lane] : 0;
        int ia = va, ib = vb;
        #pragma unroll
        for (int d = 1; d < 64; d <<= 1) {
            int oa = __shfl_up(ia, d, 64);
            int ob = __shfl_up(ib, d, 64);
            if (lane >= d) { ia += oa; ib += ob; }
        }
        if (base + lane < K) { abase[base + lane] = ca + ia - va; bbase[base + lane] = cb + ib - vb; }
        ca += __shfl(ia, 63, 64);
        cb += __shfl(ib, 63, 64);
    }
    if (lane == 0) { abase[K] = ca; bbase[K] = cb; }
}

// grid 2K x 64: convert count tables (k-major) to absolute base tables in place
__global__ void basebk_kernel(const int* __restrict__ bbase, const int* __restrict__ sbase,
                              int* __restrict__ cntD, int* __restrict__ cntS,
                              int K, int NB) {
    const bool isS = (int)blockIdx.x >= K;
    const int k = isS ? (blockIdx.x - K) : blockIdx.x;
    int* tbl = isS ? cntS : cntD;
    int run = isS ? sbase[k] : bbase[k];
    const int lane = threadIdx.x;   // 64
    for (int b0 = 0; b0 < NB; b0 += 64) {
        int v = (b0 + lane < NB) ? tbl[k * NBMAX + b0 + lane] : 0;
        int incl = v;
        #pragma unroll
        for (int d = 1; d < 64; d <<= 1) {
            int o = __shfl_up(incl, d, 64);
            if (lane >= d) incl += o;
        }
        if (b0 + lane < NB) tbl[k * NBMAX + b0 + lane] = run + incl - v;
        run += __shfl(incl, 63, 64);
    }
}

// pure streaming scatter: no LDS counting, no atomics
__global__ __launch_bounds__(256) void scatter_kernel(
        const int* __restrict__ src, const int* __restrict__ dst,
        const unsigned* __restrict__ rank,
        const int* __restrict__ baseD, const int* __restrict__ baseS,
        unsigned* __restrict__ dbuf, int* __restrict__ sbuf, int K, int E) {
    __shared__ int ldsD[KMAX], ldsS[KMAX];
    const int tid = threadIdx.x, b = blockIdx.x;
    for (int t = tid; t < K; t += 256) {
        ldsD[t] = baseD[t * NBMAX + b];
        ldsS[t] = baseS[t * NBMAX + b];
    }
    __syncthreads();
    const int base = b * EPB;
    const int lim = min(EPB, E - base);
    for (int i = tid; i < lim; i += 256) {
        int d = dst[base + i], s = src[base + i];
        unsigned r = rank[base + i];
        dbuf[ldsD[d >> BSH] + (r & 0xFFFFu)] = (unsigned)s | ((unsigned)(d & (BSZ - 1)) << 24);
        sbuf[ldsS[s >> BSH] + (r >> 16)] = s;
    }
}

// fused: blocks [0,K) build CSR; [K,2K) out_norm; [2K,..) weight conversion
__global__ __launch_bounds__(256) void finish_kernel(
        const unsigned* __restrict__ dbuf, const int* __restrict__ sbuf,
        const int* __restrict__ bbase, const int* __restrict__ sbase,
        int* __restrict__ row_ptr, float* __restrict__ in_norm,
        float* __restrict__ out_norm, int* __restrict__ col,
        const float* __restrict__ W1, const float* __restrict__ W2,
        const float* __restrict__ W3, const float* __restrict__ Wp,
        _Float16* __restrict__ WT, _Float16* __restrict__ Wph, _Float16* __restrict__ Wpr,
        int N, int K, int E) {
    __shared__ int cnt[BSZ], lsc[BSZ];
    __shared__ int wsum[4];
    const int blk = blockIdx.x, tid = threadIdx.x;

    if (blk < K) {
        // ---- build CSR for dst-bucket blk ----
        const int k = blk;
        const int node0 = k << BSH;
        const int beg = bbase[k], end = bbase[k + 1];
        cnt[tid] = 0;
        __syncthreads();
        for (int i = beg + tid; i < end; i += 256)
            atomicAdd(&cnt[dbuf[i] >> 24], 1);
        __syncthreads();
        const int c0 = cnt[tid];
        int incl = c0;
        const int lane = tid & 63, w = tid >> 6;
        #pragma unroll
        for (int d = 1; d < 64; d <<= 1) {
            int o = __shfl_up(incl, d, 64);
            if (lane >= d) incl += o;
        }
        if (lane == 63) wsum[w] = incl;
        __syncthreads();
        int off = 0;
        for (int j = 0; j < w; ++j) off += wsum[j];
        const int excl = off + incl - c0;
        lsc[tid] = excl;
        const int node = node0 + tid;
        if (node < N) { row_ptr[node] = beg + excl; in_norm[node] = 1.0f / sqrtf((float)max(c0, 1)); }
        if (k == K - 1 && tid == 0) row_ptr[N] = E;
        __syncthreads();
        cnt[tid] = 0;
        __syncthreads();
        for (int i = beg + tid; i < end; i += 256) {
            unsigned e = dbuf[i];
            int local = e >> 24;
            int r = atomicAdd(&cnt[local], 1);
            col[beg + lsc[local] + r] = (int)(e & 0xFFFFFFu);
        }
    } else if (blk < 2 * K) {
        // ---- out_norm for src-bucket blk-K ----
        const int k = blk - K;
        const int beg = sbase[k], end = sbase[k + 1];
        cnt[tid] = 0;
        __syncthreads();
        for (int i = beg + tid; i < end; i += 256)
            atomicAdd(&cnt[sbuf[i] & (BSZ - 1)], 1);
        __syncthreads();
        const int n0 = (k << BSH) + tid;
        if (n0 < N) out_norm[n0] = 1.0f / sqrtf((float)max(cnt[tid], 1));
    } else {
        // ---- weight conversion ----
        int i = (blk - 2 * K) * 256 + tid;
        if (i < 3 * HDIM * HDIM) {
            int w = i >> 14, r = i & (HDIM * HDIM - 1);
            int nn = r >> 7, kk = r & 127;
            const float* W = (w == 0) ? W1 : (w == 1) ? W2 : W3;
            WT[i] = (_Float16)W[kk * HDIM + nn];
        } else if (i < 3 * HDIM * HDIM + NCLS * HDIM) {
            int j = i - 3 * HDIM * HDIM;
            float v = Wp[j];
            _Float16 hi = (_Float16)v;
            Wph[j] = hi;
            Wpr[j] = (_Float16)(v - (float)hi);
        }
    }
}

// ---------------- dense compute ----------------

// out[m,:] = fp16( (out_norm[m]*x[m,:]) @ W ) via mfma_f32_16x16x32_f16.
// 128-row block, 2 m-tiles/wave; fp16 LDS staging; IT = float or _Float16.
template <typename IT>
__global__ __launch_bounds__(256) void gemm_mfma_kernel(
        const IT* __restrict__ x, const _Float16* __restrict__ WT,
        const float* __restrict__ out_norm, _Float16* __restrict__ out, int n) {
    __shared__ _Float16 xh[128 * 136];          // 34.8 KB; also epilogue cs
    const int tid = threadIdx.x;
    const int wave = tid >> 6, lane = tid & 63;
    const int quad = lane >> 4, cI = lane & 15;
    const int row0 = blockIdx.x * 128;

    for (int t = tid; t < 128 * 16; t += 256) {
        int r = t >> 4, c8 = t & 15;
        int gr = row0 + r;
        half8 hv = {};
        if (gr < n) {
            float sc = out_norm[gr];
            if constexpr (sizeof(IT) == 2) {
                half8 v = *(const half8*)((const _Float16*)x + (size_t)gr * HDIM + c8 * 8);
                #pragma unroll
                for (int q = 0; q < 8; ++q) hv[q] = (_Float16)((float)v[q] * sc);
            } else {
                const float* xr = (const float*)x + (size_t)gr * HDIM + c8 * 8;
                float4 u = *(const float4*)xr;
                float4 v = *(const float4*)(xr + 4);
                hv[0] = (_Float16)(u.x * sc); hv[1] = (_Float16)(u.y * sc);
                hv[2] = (_Float16)(u.z * sc); hv[3] = (_Float16)(u.w * sc);
                hv[4] = (_Float16)(v.x * sc); hv[5] = (_Float16)(v.y * sc);
                hv[6] = (_Float16)(v.z * sc); hv[7] = (_Float16)(v.w * sc);
            }
        }
        *(half8*)&xh[r * 136 + c8 * 8] = hv;
    }
    __syncthreads();

    half8 afr[2][4];
    #pragma unroll
    for (int i = 0; i < 2; ++i) {
        int mrow = wave * 32 + i * 16 + cI;
        #pragma unroll
        for (int kc = 0; kc < 4; ++kc)
            afr[i][kc] = *(const half8*)&xh[mrow * 136 + kc * 32 + quad * 8];
    }
    __syncthreads();

    f32x4 acc[2][8];
    #pragma unroll
    for (int i = 0; i < 2; ++i)
        #pragma unroll
        for (int nt = 0; nt < 8; ++nt) acc[i][nt] = (f32x4){0.f, 0.f, 0.f, 0.f};

    #pragma unroll
    for (int nt = 0; nt < 8; ++nt) {
        const _Float16* wb = WT + (size_t)(nt * 16 + cI) * HDIM + quad * 8;
        half8 bfr[4];
        #pragma unroll
        for (int kc = 0; kc < 4; ++kc) bfr[kc] = *(const half8*)(wb + kc * 32);
        #pragma unroll
        for (int i = 0; i < 2; ++i)
            #pragma unroll
            for (int kc = 0; kc < 4; ++kc)
                acc[i][nt] = __builtin_amdgcn_mfma_f32_16x16x32_f16(afr[i][kc], bfr[kc], acc[i][nt], 0, 0, 0);
    }

    _Float16 (*cs)[136] = (_Float16(*)[136])xh;
    #pragma unroll
    for (int i = 0; i < 2; ++i)
        #pragma unroll
        for (int nt = 0; nt < 8; ++nt)
            #pragma unroll
            for (int r = 0; r < 4; ++r)
                cs[wave * 32 + i * 16 + quad * 4 + r][nt * 16 + cI] = (_Float16)acc[i][nt][r];
    __syncthreads();

    for (int t = tid; t < 128 * 16; t += 256) {
        int r = t >> 4, c8 = t & 15;
        int gr = row0 + r;
        if (gr < n)
            *(float4*)(out + (size_t)gr * HDIM + c8 * 8) = *(float4*)&cs[r][c8 * 8];
    }
}

// accumulate one 16-B fp16 chunk into 8 fp32 sums
__device__ __forceinline__ void acc16(const float4& r, float* f) {
    const __half2* p = (const __half2*)&r;
    #pragma unroll
    for (int q = 0; q < 4; ++q) {
        float2 g = __half22float2(p[q]);
        f[2 * q]     += g.x;
        f[2 * q + 1] += g.y;
    }
}

// fp16 gather: h[n,:] = relu(in_norm[n]*sum t[col[e],:] + b) — one wave/node,
// 16-lane groups x 4 edges in flight. Output fp16.
__global__ __launch_bounds__(256) void agg_h_kernel(
        const _Float16* __restrict__ t, const int* __restrict__ row_ptr,
        const int* __restrict__ col, const float* __restrict__ in_norm,
        const float* __restrict__ bias, _Float16* __restrict__ h, int n) {
    int node = blockIdx.x * 4 + (threadIdx.x >> 6);
    if (node >= n) return;
    const int lane = threadIdx.x & 63;
    const int eg = lane >> 4;       // edge group 0..3
    const int fq = lane & 15;       // 16-B feature chunk
    const int beg = row_ptr[node], end = row_ptr[node + 1];
    float f0[8] = {}, f1[8] = {}, f2[8] = {}, f3[8] = {};
    for (int e = beg; e < end; e += 64) {
        int cnt = min(64, end - e);
        int ci = (lane < cnt) ? col[e + lane] : 0;
        for (int j = 0; j < cnt; j += 16) {
            int s0 = __shfl(ci, j + eg, 64);
            int s1 = __shfl(ci, j + 4 + eg, 64);
            int s2 = __shfl(ci, j + 8 + eg, 64);
            int s3 = __shfl(ci, j + 12 + eg, 64);
            float4 r0 = {0.f,0.f,0.f,0.f}, r1 = {0.f,0.f,0.f,0.f};
            float4 r2 = {0.f,0.f,0.f,0.f}, r3 = {0.f,0.f,0.f,0.f};
            if (j + eg < cnt)      r0 = ((const float4*)(t + (size_t)s0 * HDIM))[fq];
            if (j + 4 + eg < cnt)  r1 = ((const float4*)(t + (size_t)s1 * HDIM))[fq];
            if (j + 8 + eg < cnt)  r2 = ((const float4*)(t + (size_t)s2 * HDIM))[fq];
            if (j + 12 + eg < cnt) r3 = ((const float4*)(t + (size_t)s3 * HDIM))[fq];
            acc16(r0, f0);
            acc16(r1, f1);
            acc16(r2, f2);
            acc16(r3, f3);
        }
    }
    float f[8];
    #pragma unroll
    for (int q = 0; q < 8; ++q) f[q] = (f0[q] + f1[q]) + (f2[q] + f3[q]);
    #pragma unroll
    for (int q = 0; q < 8; ++q) f[q] += __shfl_xor(f[q], 16, 64);
    #pragma unroll
    for (int q = 0; q < 8; ++q) f[q] += __shfl_xor(f[q], 32, 64);
    if (eg == 0) {
        float inn = in_norm[node];
        float4 b0 = ((const float4*)bias)[2 * fq];
        float4 b1 = ((const float4*)bias)[2 * fq + 1];
        half8 hv;
        hv[0] = (_Float16)fmaxf(f[0] * inn + b0.x, 0.f);
        hv[1] = (_Float16)fmaxf(f[1] * inn + b0.y, 0.f);
        hv[2] = (_Float16)fmaxf(f[2] * inn + b0.z, 0.f);
        hv[3] = (_Float16)fmaxf(f[3] * inn + b0.w, 0.f);
        hv[4] = (_Float16)fmaxf(f[4] * inn + b1.x, 0.f);
        hv[5] = (_Float16)fmaxf(f[5] * inn + b1.y, 0.f);
        hv[6] = (_Float16)fmaxf(f[6] * inn + b1.z, 0.f);
        hv[7] = (_Float16)fmaxf(f[7] * inn + b1.w, 0.f);
        *(half8*)(h + (size_t)node * HDIM + fq * 8) = hv;
    }
}

__global__ void seg_kernel(const float* __restrict__ colsum, const float* __restrict__ Wp,
                           const float* __restrict__ bp, float* __restrict__ segout, float inv_n) {
    int c = threadIdx.x;
    if (c < NCLS) {
        float s = 0.f;
        #pragma unroll 4
        for (int k = 0; k < HDIM; ++k) s = fmaf(colsum[k], Wp[c * HDIM + k], s);
        segout[c] = s * inv_n + bp[c];
    }
}

// CAM via MFMA: CAM[c,n] = dot(Wp[c,:], h3[n,:]).
// Block = 128 nodes staged in LDS; per class-tile A load (~60 live VGPRs).
__global__ __launch_bounds__(256) void cam_mfma_kernel(
        const _Float16* __restrict__ h, const _Float16* __restrict__ Wph,
        const _Float16* __restrict__ Wpr, float* __restrict__ out,
        float* __restrict__ colsum, int n) {
    __shared__ _Float16 hs[128 * CSTRIDE];      // 35 KB
    const int tid = threadIdx.x;
    const int wave = tid >> 6, lane = tid & 63;
    const int quad = lane >> 4, cI = lane & 15;
    const int n0 = blockIdx.x * 128;

    for (int t = tid; t < 128 * 16; t += 256) {
        int r = t >> 4, c8 = t & 15;
        int gr = n0 + r;
        half8 v = {};
        if (gr < n) v = *(const half8*)(h + (size_t)gr * HDIM + c8 * 8);
        *(half8*)&hs[r * CSTRIDE + c8 * 8] = v;
    }
    __syncthreads();

    #pragma unroll
    for (int ct = 0; ct < 3; ++ct) {
        const int cls = ct * 16 + cI;
        const bool av = cls < NCLS;
        const int clc = av ? cls : 0;
        half8 ah[4], ar[4];
        #pragma unroll
        for (int kc = 0; kc < 4; ++kc) {
            half8 z = {};
            half8 vh = *(const half8*)(Wph + clc * HDIM + kc * 32 + quad * 8);
            half8 vr = *(const half8*)(Wpr + clc * HDIM + kc * 32 + quad * 8);
            ah[kc] = av ? vh : z;
            ar[kc] = av ? vr : z;
        }
        #pragma unroll
        for (int t = 0; t < 2; ++t) {
            const int ln = wave * 32 + t * 16 + cI;
            f32x4 acc = (f32x4){0.f, 0.f, 0.f, 0.f};
            #pragma unroll
            for (int kc = 0; kc < 4; ++kc) {
                half8 b = *(const half8*)&hs[ln * CSTRIDE + kc * 32 + quad * 8];
                acc = __builtin_amdgcn_mfma_f32_16x16x32_f16(ah[kc], b, acc, 0, 0, 0);
                acc = __builtin_amdgcn_mfma_f32_16x16x32_f16(ar[kc], b, acc, 0, 0, 0);
            }
            const int node = n0 + ln;
            #pragma unroll
            for (int r = 0; r < 4; ++r) {
                int c2 = ct * 16 + quad * 4 + r;
                if (c2 < NCLS && node < n)
                    out[(size_t)c2 * n + node] = acc[r];
            }
        }
    }

    if (tid < HDIM) {
        float s = 0.f;
        for (int r = 0; r < 128; ++r) s += (float)hs[r * CSTRIDE + tid];
        atomicAdd(&colsum[tid], s);
    }
}

// ---------------- launch ----------------

extern "C" void kernel_launch(void* const* d_in, const int* in_sizes, int n_in,
                              void* d_out, int out_size, void* d_ws, size_t ws_size,
                              hipStream_t stream) {
    const float* features = (const float*)d_in[0];
    const float* W1 = (const float*)d_in[1];
    const float* b1 = (const float*)d_in[2];
    const float* W2 = (const float*)d_in[3];
    const float* b2 = (const float*)d_in[4];
    const float* W3 = (const float*)d_in[5];
    const float* b3 = (const float*)d_in[6];
    const float* Wp = (const float*)d_in[7];
    const float* bp = (const float*)d_in[8];
    const int*   src = (const int*)d_in[9];
    const int*   dst = (const int*)d_in[10];

    const int N = in_sizes[0] / HDIM;
    const int E = in_sizes[9];
    const int K = (N + BSZ - 1) >> BSH;           // buckets (<= KMAX)
    const int NB = (E + EPB - 1) / EPB;           // <= NBMAX
    float* out = (float*)d_out;

    // workspace carve-up
    char* ws = (char*)d_ws;
    size_t off = 0;
    int* bcnt   = (int*)(ws + off); off += KMAX * 4;
    int* sbcnt  = (int*)(ws + off); off += KMAX * 4;
    float* colsum = (float*)(ws + off); off += 128 * 4;
    int* bbase  = (int*)(ws + off); off += (KMAX + 1) * 4;
    int* sbase  = (int*)(ws + off); off += (KMAX + 1) * 4;
    int* cntD   = (int*)(ws + off); off += (size_t)KMAX * NBMAX * 4;   // -> baseD
    int* cntS   = (int*)(ws + off); off += (size_t)KMAX * NBMAX * 4;   // -> baseS
    int* row_ptr = (int*)(ws + off); off += ((size_t)N + 1) * 4; off = (off + 15) & ~(size_t)15;
    int* col_idx = (int*)(ws + off); off += (size_t)E * 4; off = (off + 15) & ~(size_t)15;
    float* out_norm = (float*)(ws + off); off += (size_t)N * 4;
    float* in_norm  = (float*)(ws + off); off += (size_t)N * 4; off = (off + 255) & ~(size_t)255;
    _Float16* WT  = (_Float16*)(ws + off); off += 3 * HDIM * HDIM * 2;
    _Float16* Wph = (_Float16*)(ws + off); off += NCLS * HDIM * 2;
    _Float16* Wpr = (_Float16*)(ws + off); off += NCLS * HDIM * 2; off = (off + 255) & ~(size_t)255;
    _Float16* Bh  = (_Float16*)(ws + off); off += (size_t)N * HDIM * 2; off = (off + 255) & ~(size_t)255;
    _Float16* F0h = (_Float16*)(ws + off); off += (size_t)N * HDIM * 2; off = (off + 255) & ~(size_t)255;
    (void)ws_size; (void)n_in; (void)out_size;

    // aliases: rank in Bh (first written by gemm1); dbuf/sbuf in F0h (first
    // written by agg1, after finish_kernel consumed them)
    unsigned* rank = (unsigned*)Bh;                   // E*4 B
    unsigned* dbuf = (unsigned*)F0h;                  // E*4 B (packed src|local<<24)
    int*      sbuf = (int*)((char*)F0h + (size_t)E * 4);  // E*4 B

    const int nzero = 2 * KMAX + 128;
    zero_kernel<<<(nzero + 255) / 256, 256, 0, stream>>>((int*)ws, nzero);
    count_rank_kernel<<<NB, 256, 0, stream>>>(src, dst, bcnt, sbcnt, rank, cntD, cntS, K, E);
    bucket_scan_kernel<<<1, 64, 0, stream>>>(bcnt, sbcnt, bbase, sbase, K);
    basebk_kernel<<<2 * K, 64, 0, stream>>>(bbase, sbase, cntD, cntS, K, NB);
    scatter_kernel<<<NB, 256, 0, stream>>>(src, dst, rank, cntD, cntS, dbuf, sbuf, K, E);

    const int conv_blocks = (3 * HDIM * HDIM + NCLS * HDIM + 255) / 256;
    finish_kernel<<<2 * K + conv_blocks, 256, 0, stream>>>(
        dbuf, sbuf, bbase, sbase, row_ptr, in_norm, out_norm, col_idx,
        W1, W2, W3, Wp, WT, Wph, Wpr, N, K, E);

    const int gemm_blocks = (N + 127) / 128;
    const int agg_blocks  = (N + 3) / 4;

    // layer 1
    gemm_mfma_kernel<float><<<gemm_blocks, 256, 0, stream>>>(features, WT, out_norm, Bh, N);
    agg_h_kernel<<<agg_blocks, 256, 0, stream>>>(Bh, row_ptr, col_idx, in_norm, b1, F0h, N);
    // layer 2
    gemm_mfma_kernel<_Float16><<<gemm_blocks, 256, 0, stream>>>(F0h, WT + HDIM * HDIM, out_norm, Bh, N);
    agg_h_kernel<<<agg_blocks, 256, 0, stream>>>(Bh, row_ptr, col_idx, in_norm, b2, F0h, N);
    // layer 3 (h3 fp16 -> F0h)
    gemm_mfma_kernel<_Float16><<<gemm_blocks, 256, 0, stream>>>(F0h, WT + 2 * HDIM * HDIM, out_norm, Bh, N);
    agg_h_kernel<<<agg_blocks, 256, 0, stream>>>(Bh, row_ptr, col_idx, in_norm, b3, F0h, N);

    // head: cam (MFMA, fused colsum) then seg
    cam_mfma_kernel<<<(N + 127) / 128, 256, 0, stream>>>(F0h, Wph, Wpr, out + NCLS, colsum, N);
    seg_kernel<<<1, 64, 0, stream>>>(colsum, Wp, bp, out, 1.0f / (float)N);
}